// Round 1
// baseline (275.280 us; speedup 1.0000x reference)
//
#include <hip/hip_runtime.h>

#define BB 2
#define SS 2048
#define DDIM 1024
#define HH 16
#define DEPTH 64
#define QKVN (3*DDIM)

typedef unsigned short u16;
typedef unsigned int u32;
typedef __attribute__((ext_vector_type(8))) short bf16x8;
typedef __attribute__((ext_vector_type(4))) float f32x4;

__device__ __forceinline__ u16 f2bf(float f){
  union{float f; u32 u;} z; z.f=f;
  u32 r = z.u + 0x7fffu + ((z.u>>16)&1u);
  return (u16)(r>>16);
}
#define NEG_BIG (-1e30f)

// async global->LDS, 16B per lane (guide m97); LDS dest must be wave-linear (ours is tid*16B)
#define GL2LDS(gp, lp) __builtin_amdgcn_global_load_lds( \
    (const __attribute__((address_space(1))) void*)(gp), \
    (__attribute__((address_space(3))) void*)(lp), 16, 0, 0)

// ---------------- transpose+convert f32 [R,C] -> bf16 [C,R] ----------------
__global__ void convT_k(const float* __restrict__ in, u16* __restrict__ out, int R, int C){
  __shared__ float tile[32][33];
  int c0 = blockIdx.x<<5, r0 = blockIdx.y<<5;
  int tx = threadIdx.x, ty = threadIdx.y;
  for (int i=ty;i<32;i+=8) tile[i][tx] = in[(size_t)(r0+i)*C + c0+tx];
  __syncthreads();
  for (int i=ty;i<32;i+=8) out[(size_t)(c0+i)*R + r0+tx] = f2bf(tile[tx][i]);
}

// ---------------- convert f32 -> bf16 flat (both batches) ----------------
__global__ void convX_k(const float* __restrict__ in, u16* __restrict__ out){
  size_t i = ((size_t)blockIdx.x*256 + threadIdx.x) * 8;
  float4 a = *(const float4*)(in + i);
  float4 b = *(const float4*)(in + i + 4);
  ushort4 lo = { f2bf(a.x), f2bf(a.y), f2bf(a.z), f2bf(a.w) };
  ushort4 hi = { f2bf(b.x), f2bf(b.y), f2bf(b.z), f2bf(b.w) };
  *(ushort4*)(out + i)     = lo;
  *(ushort4*)(out + i + 4) = hi;
}

// ---------------- QKV GEMM (m97-style: global_load_lds staging) ----------------
// [4096,1024]@[1024,3072]^T. Epilogue splits into Qb (x0.125), Kb, Vt (V transposed).
__global__ __launch_bounds__(256,2) void gemm_qkv_k(
    const u16* __restrict__ A, const u16* __restrict__ Bt,
    const float* __restrict__ bias,
    u16* __restrict__ Qb, u16* __restrict__ Kb, u16* __restrict__ Vt)
{
  const int K = DDIM;
  __shared__ __align__(16) u16 As[128*32];
  __shared__ __align__(16) u16 Bs[128*32];
  const int tid = threadIdx.x;
  const int m0 = blockIdx.x<<7, n0 = blockIdx.y<<7;
  const int w = tid>>6, lane = tid&63, q = lane>>4, ln = lane&15;
  const int wr = (w>>1)<<6, wc = (w&1)<<6;

  f32x4 acc[4][4];
  #pragma unroll
  for (int i=0;i<4;i++)
    #pragma unroll
    for (int j=0;j<4;j++) acc[i][j] = (f32x4){0.f,0.f,0.f,0.f};

  const int row0 = tid>>2,         off0 = (tid&3)<<3;
  const int row1 = (tid+256)>>2,   off1 = (tid&3)<<3;   // (tid+256)&3 == tid&3

  for (int k0=0;k0<K;k0+=32){
    GL2LDS(&A [(size_t)(m0+row0)*K + k0 + off0], &As[(row0<<5)+off0]);
    GL2LDS(&Bt[(size_t)(n0+row0)*K + k0 + off0], &Bs[(row0<<5)+off0]);
    GL2LDS(&A [(size_t)(m0+row1)*K + k0 + off1], &As[(row1<<5)+off1]);
    GL2LDS(&Bt[(size_t)(n0+row1)*K + k0 + off1], &Bs[(row1<<5)+off1]);
    __syncthreads();
    bf16x8 af[4], bfr[4];
    #pragma unroll
    for (int i=0;i<4;i++) af[i]  = *(const bf16x8*)&As[((wr + (i<<4) + ln)<<5) + (q<<3)];
    #pragma unroll
    for (int j=0;j<4;j++) bfr[j] = *(const bf16x8*)&Bs[((wc + (j<<4) + ln)<<5) + (q<<3)];
    #pragma unroll
    for (int i=0;i<4;i++)
      #pragma unroll
      for (int j=0;j<4;j++)
        acc[i][j] = __builtin_amdgcn_mfma_f32_16x16x32_bf16(af[i], bfr[j], acc[i][j], 0, 0, 0);
    __syncthreads();
  }

  #pragma unroll
  for (int i=0;i<4;i++){
    const int mmb = m0 + wr + (i<<4) + (q<<2);         // global row (4096 range)
    const int bsel = mmb >> 11;                        // batch (uniform per block)
    const int sb   = mmb & 2047;                       // s within batch
    #pragma unroll
    for (int j=0;j<4;j++){
      const int n = n0 + wc + (j<<4) + ln;
      const int h = n / 192;
      const int rr = n - h*192;
      const int bh = (bsel<<4) + h;
      const float bv = bias[n];
      if (rr < 64){                                    // Q, scaled by 1/8
        u16* dst = Qb + (size_t)bh*SS*DEPTH + rr;
        #pragma unroll
        for (int r=0;r<4;r++) dst[(size_t)(sb+r)*DEPTH] = f2bf((acc[i][j][r] + bv)*0.125f);
      } else if (rr < 128){                            // K
        u16* dst = Kb + (size_t)bh*SS*DEPTH + (rr-64);
        #pragma unroll
        for (int r=0;r<4;r++) dst[(size_t)(sb+r)*DEPTH] = f2bf(acc[i][j][r] + bv);
      } else {                                         // V transposed: Vt[bh][d][s]
        ushort4 pv = { f2bf(acc[i][j][0] + bv), f2bf(acc[i][j][1] + bv),
                       f2bf(acc[i][j][2] + bv), f2bf(acc[i][j][3] + bv) };
        *(ushort4*)(Vt + ((size_t)bh*DEPTH + (rr-128))*SS + sb) = pv;
      }
    }
  }
}

// ---------------- MFMA flash attention, barrier-free ----------------
// K/V fragments are read DIRECTLY from global (L1/L2-resident: per-XCD L2 holds its
// 4 heads' K+V = 2MB < 4MB via bh%8 pinning; fragment reads are 16B-contiguous in the
// global layouts K[s][64] and Vt[d][s]).  No LDS staging => no __syncthreads at all;
// ps is strictly per-wave (compiler orders via lgkmcnt).  4 blocks/CU, 16 indep waves.
__global__ __launch_bounds__(256,4) void attn_k(
    u16* __restrict__ Qb, const u16* __restrict__ Kb, const u16* __restrict__ Vt)
{
  __shared__ __align__(16) u16 ps[4][16*72];   // per-wave P [m][j], stride 72

  const int tid = threadIdx.x, w = tid>>6, lane = tid&63, q = lane>>4, ln = lane&15;
  const int bh = blockIdx.x;                   // b*16 + h  (XCD = bh%8)
  const int y  = blockIdx.y, sgrp = y>>3, rr_ = y&7;
  const int qt = (sgrp==0) ? 31-rr_ : (sgrp==1) ? 16+rr_ : (sgrp==2) ? 15-rr_ : rr_;
  const int r0 = qt<<6;
  const size_t kbase = (size_t)bh*SS*DEPTH;    // Kb/Qb per-(b,h) base
  const size_t vbase = (size_t)bh*DEPTH*SS;    // Vt per-(b,h) base
  const u16* __restrict__ Kp = Kb + kbase;
  const u16* __restrict__ Vp = Vt + vbase;

  bf16x8 qf[2];
  #pragma unroll
  for (int ks=0;ks<2;ks++)
    qf[ks] = *(const bf16x8*)(Qb + kbase + (size_t)(r0 + (w<<4) + ln)*DEPTH + (ks<<5) + (q<<3));

  f32x4 o[4];
  #pragma unroll
  for (int nt=0;nt<4;nt++) o[nt] = (f32x4){0.f,0.f,0.f,0.f};
  float m_r[4], l_r[4];
  #pragma unroll
  for (int r=0;r<4;r++){ m_r[r] = NEG_BIG; l_r[r] = 0.f; }

  const int T = qt + 1;
  for (int t=0;t<T;t++){
    // QK^T  (kf straight from global; 16B per lane, L1/L2 hit)
    const u16* kp = Kp + ((size_t)(t<<6) + ln)*DEPTH + (q<<3);
    f32x4 sc[4];
    #pragma unroll
    for (int jt=0;jt<4;jt++) sc[jt] = (f32x4){0.f,0.f,0.f,0.f};
    #pragma unroll
    for (int ks=0;ks<2;ks++){
      #pragma unroll
      for (int jt=0;jt<4;jt++){
        bf16x8 kf = *(const bf16x8*)(kp + (size_t)(jt<<4)*DEPTH + (ks<<5));
        sc[jt] = __builtin_amdgcn_mfma_f32_16x16x32_bf16(qf[ks], kf, sc[jt], 0, 0, 0);
      }
    }

    // causal mask on diagonal tile
    if (t == T-1){
      const int rowb = r0 + (w<<4) + (q<<2);
      #pragma unroll
      for (int jt=0;jt<4;jt++){
        const int col = (t<<6) + (jt<<4) + ln;
        #pragma unroll
        for (int r=0;r<4;r++)
          if (col > rowb + r) sc[jt][r] = NEG_BIG;
      }
    }

    // online softmax per row (row lives on 16 lanes sharing quad q)
    float alpha_r[4];
    #pragma unroll
    for (int r=0;r<4;r++){
      float mt = fmaxf(fmaxf(sc[0][r], sc[1][r]), fmaxf(sc[2][r], sc[3][r]));
      #pragma unroll
      for (int off=1; off<16; off<<=1) mt = fmaxf(mt, __shfl_xor(mt, off));
      const float mnew = fmaxf(m_r[r], mt);
      alpha_r[r] = __expf(m_r[r] - mnew);
      float p0 = __expf(sc[0][r]-mnew), p1 = __expf(sc[1][r]-mnew);
      float p2 = __expf(sc[2][r]-mnew), p3 = __expf(sc[3][r]-mnew);
      const int mrow = (q<<2) + r;
      ps[w][mrow*72 +      ln] = f2bf(p0);
      ps[w][mrow*72 + 16 + ln] = f2bf(p1);
      ps[w][mrow*72 + 32 + ln] = f2bf(p2);
      ps[w][mrow*72 + 48 + ln] = f2bf(p3);
      float psum = (p0+p1)+(p2+p3);
      #pragma unroll
      for (int off=1; off<16; off<<=1) psum += __shfl_xor(psum, off);
      l_r[r] = l_r[r]*alpha_r[r] + psum;
      m_r[r] = mnew;
    }
    #pragma unroll
    for (int nt=0;nt<4;nt++)
      #pragma unroll
      for (int r=0;r<4;r++) o[nt][r] *= alpha_r[r];

    // PV (ps is per-wave: no barrier needed; vf straight from global Vt[d][s])
    const u16* vp = Vp + (size_t)ln*SS + (t<<6) + (q<<3);
    #pragma unroll
    for (int ks=0;ks<2;ks++){
      bf16x8 pa = *(const bf16x8*)&ps[w][ln*72 + (ks<<5) + (q<<3)];
      #pragma unroll
      for (int nt=0;nt<4;nt++){
        bf16x8 vf = *(const bf16x8*)(vp + (size_t)(nt<<4)*SS + (ks<<5));
        o[nt] = __builtin_amdgcn_mfma_f32_16x16x32_bf16(pa, vf, o[nt], 0, 0, 0);
      }
    }
  }

  // epilogue: o/l -> bf16, overwrite this block's own Qb rows
  #pragma unroll
  for (int r=0;r<4;r++){
    const float rl = 1.f / fmaxf(l_r[r], 1e-30f);
    const int s = r0 + (w<<4) + (q<<2) + r;
    #pragma unroll
    for (int nt=0;nt<4;nt++)
      Qb[kbase + (size_t)s*DEPTH + (nt<<4) + ln] = f2bf(o[nt][r] * rl);
  }
}

// ---------------- out projection (m97-style staging), both batches, f32 out ----------------
// A(m,k) = Qb[(m>>11)*16 + k/64][m&2047][k%64]
__global__ __launch_bounds__(256,2) void gemm_out_k(
    const u16* __restrict__ Aq, const u16* __restrict__ Bt,
    const float* __restrict__ bias, float* __restrict__ out)
{
  const int K = DDIM;
  __shared__ __align__(16) u16 As[128*32];
  __shared__ __align__(16) u16 Bs[128*32];
  const int tid = threadIdx.x;
  const int m0 = blockIdx.x<<7, n0 = blockIdx.y<<7;
  const int bsel = m0>>11, ms = m0&2047;       // batch select (uniform per block)
  const int w = tid>>6, lane = tid&63, q = lane>>4, ln = lane&15;
  const int wr = (w>>1)<<6, wc = (w&1)<<6;

  f32x4 acc[4][4];
  #pragma unroll
  for (int i=0;i<4;i++)
    #pragma unroll
    for (int j=0;j<4;j++) acc[i][j] = (f32x4){0.f,0.f,0.f,0.f};

  const int row0 = tid>>2,       off0 = (tid&3)<<3;
  const int row1 = (tid+256)>>2, off1 = (tid&3)<<3;

  for (int k0=0;k0<K;k0+=32){
    const size_t abase = (size_t)((bsel<<4) + (k0>>6))*SS*DEPTH + (k0&63);
    GL2LDS(&Aq[abase + (size_t)(ms+row0)*DEPTH + off0], &As[(row0<<5)+off0]);
    GL2LDS(&Bt[(size_t)(n0+row0)*K + k0 + off0],        &Bs[(row0<<5)+off0]);
    GL2LDS(&Aq[abase + (size_t)(ms+row1)*DEPTH + off1], &As[(row1<<5)+off1]);
    GL2LDS(&Bt[(size_t)(n0+row1)*K + k0 + off1],        &Bs[(row1<<5)+off1]);
    __syncthreads();
    bf16x8 af[4], bfr[4];
    #pragma unroll
    for (int i=0;i<4;i++) af[i]  = *(const bf16x8*)&As[((wr + (i<<4) + ln)<<5) + (q<<3)];
    #pragma unroll
    for (int j=0;j<4;j++) bfr[j] = *(const bf16x8*)&Bs[((wc + (j<<4) + ln)<<5) + (q<<3)];
    #pragma unroll
    for (int i=0;i<4;i++)
      #pragma unroll
      for (int j=0;j<4;j++)
        acc[i][j] = __builtin_amdgcn_mfma_f32_16x16x32_bf16(af[i], bfr[j], acc[i][j], 0, 0, 0);
    __syncthreads();
  }

  #pragma unroll
  for (int i=0;i<4;i++){
    #pragma unroll
    for (int j=0;j<4;j++){
      const int n = n0 + wc + (j<<4) + ln;
      const float bv = bias[n];
      #pragma unroll
      for (int r=0;r<4;r++){
        const int mm = m0 + wr + (i<<4) + (q<<2) + r;
        out[(size_t)mm*DDIM + n] = acc[i][j][r] + bv;
      }
    }
  }
}

extern "C" void kernel_launch(void* const* d_in, const int* in_sizes, int n_in,
                              void* d_out, int out_size, void* d_ws, size_t ws_size,
                              hipStream_t stream)
{
  int ix = 0, iw = 2, ibq = 3, iwo = 4, ibo = 5;
  if (n_in == 5){ iw = 1; ibq = 2; iwo = 3; ibo = 4; }
  const float* x  = (const float*)d_in[ix];
  const float* Wq = (const float*)d_in[iw];
  const float* bq = (const float*)d_in[ibq];
  const float* Wo = (const float*)d_in[iwo];
  const float* bo = (const float*)d_in[ibo];
  float* out = (float*)d_out;

  // workspace (u16 units), total 41,943,040 B — round-1-proven footprint
  u16* ws  = (u16*)d_ws;
  u16* Wqt = ws;                                   // [3072,1024] bf16
  u16* Wot = Wqt + (size_t)QKVN*DDIM;              // [1024,1024] bf16 (bt form)
  u16* Qb  = Wot + (size_t)DDIM*DDIM;              // [B*H][S][64]; attn out aliases here
  u16* Kb  = Qb  + (size_t)BB*HH*SS*DEPTH;         // [B*H][S][64]
  u16* Vt  = Kb  + (size_t)BB*HH*SS*DEPTH;         // [B*H][64][S] (V transposed)
  u16* xb  = Vt  + (size_t)BB*HH*SS*DEPTH;         // [2,2048,1024] bf16

  convT_k<<<dim3(QKVN/32, DDIM/32), dim3(32,8), 0, stream>>>(Wq, Wqt, DDIM, QKVN);
  convT_k<<<dim3(DDIM/32, DDIM/32), dim3(32,8), 0, stream>>>(Wo, Wot, DDIM, DDIM);
  convX_k<<<dim3(BB*SS*DDIM/2048), 256, 0, stream>>>(x, xb);

  gemm_qkv_k<<<dim3(BB*SS/128, QKVN/128), 256, 0, stream>>>(xb, Wqt, bq, Qb, Kb, Vt);
  attn_k    <<<dim3(BB*HH, 32),           256, 0, stream>>>(Qb, Kb, Vt);
  gemm_out_k<<<dim3(BB*SS/128, DDIM/128), 256, 0, stream>>>(Qb, Wot, bo, out);
}

// Round 5
// 213.017 us; speedup vs baseline: 1.2923x; 1.2923x over previous
//
#include <hip/hip_runtime.h>

#define BB 2
#define SS 2048
#define DDIM 1024
#define HH 16
#define DEPTH 64
#define QKVN (3*DDIM)

typedef unsigned short u16;
typedef unsigned int u32;
typedef __attribute__((ext_vector_type(8))) short bf16x8;
typedef __attribute__((ext_vector_type(4))) float f32x4;

__device__ __forceinline__ u16 f2bf(float f){
  union{float f; u32 u;} z; z.f=f;
  u32 r = z.u + 0x7fffu + ((z.u>>16)&1u);
  return (u16)(r>>16);
}
#define NEG_BIG (-1e30f)

// async global->LDS, 16B per lane (guide m97); LDS dest must be wave-linear (ours is tid*16B)
#define GL2LDS(gp, lp) __builtin_amdgcn_global_load_lds( \
    (const __attribute__((address_space(1))) void*)(gp), \
    (__attribute__((address_space(3))) void*)(lp), 16, 0, 0)

// ---------------- transpose+convert f32 [R,C] -> bf16 [C,R] ----------------
__global__ void convT_k(const float* __restrict__ in, u16* __restrict__ out, int R, int C){
  __shared__ float tile[32][33];
  int c0 = blockIdx.x<<5, r0 = blockIdx.y<<5;
  int tx = threadIdx.x, ty = threadIdx.y;
  for (int i=ty;i<32;i+=8) tile[i][tx] = in[(size_t)(r0+i)*C + c0+tx];
  __syncthreads();
  for (int i=ty;i<32;i+=8) out[(size_t)(c0+i)*R + r0+tx] = f2bf(tile[tx][i]);
}

// ---------------- convert f32 -> bf16 flat (both batches) ----------------
__global__ void convX_k(const float* __restrict__ in, u16* __restrict__ out){
  size_t i = ((size_t)blockIdx.x*256 + threadIdx.x) * 8;
  float4 a = *(const float4*)(in + i);
  float4 b = *(const float4*)(in + i + 4);
  ushort4 lo = { f2bf(a.x), f2bf(a.y), f2bf(a.z), f2bf(a.w) };
  ushort4 hi = { f2bf(b.x), f2bf(b.y), f2bf(b.z), f2bf(b.w) };
  *(ushort4*)(out + i)     = lo;
  *(ushort4*)(out + i + 4) = hi;
}

// ---------------- QKV GEMM (m97-style: global_load_lds staging) ----------------
// [4096,1024]@[1024,3072]^T. Epilogue splits into Qb (x0.125), Kb, Vt (V transposed).
__global__ __launch_bounds__(256,2) void gemm_qkv_k(
    const u16* __restrict__ A, const u16* __restrict__ Bt,
    const float* __restrict__ bias,
    u16* __restrict__ Qb, u16* __restrict__ Kb, u16* __restrict__ Vt)
{
  const int K = DDIM;
  __shared__ __align__(16) u16 As[128*32];
  __shared__ __align__(16) u16 Bs[128*32];
  const int tid = threadIdx.x;
  const int m0 = blockIdx.x<<7, n0 = blockIdx.y<<7;
  const int w = tid>>6, lane = tid&63, q = lane>>4, ln = lane&15;
  const int wr = (w>>1)<<6, wc = (w&1)<<6;

  f32x4 acc[4][4];
  #pragma unroll
  for (int i=0;i<4;i++)
    #pragma unroll
    for (int j=0;j<4;j++) acc[i][j] = (f32x4){0.f,0.f,0.f,0.f};

  const int row0 = tid>>2,         off0 = (tid&3)<<3;
  const int row1 = (tid+256)>>2,   off1 = (tid&3)<<3;   // (tid+256)&3 == tid&3

  for (int k0=0;k0<K;k0+=32){
    GL2LDS(&A [(size_t)(m0+row0)*K + k0 + off0], &As[(row0<<5)+off0]);
    GL2LDS(&Bt[(size_t)(n0+row0)*K + k0 + off0], &Bs[(row0<<5)+off0]);
    GL2LDS(&A [(size_t)(m0+row1)*K + k0 + off1], &As[(row1<<5)+off1]);
    GL2LDS(&Bt[(size_t)(n0+row1)*K + k0 + off1], &Bs[(row1<<5)+off1]);
    __syncthreads();
    bf16x8 af[4], bfr[4];
    #pragma unroll
    for (int i=0;i<4;i++) af[i]  = *(const bf16x8*)&As[((wr + (i<<4) + ln)<<5) + (q<<3)];
    #pragma unroll
    for (int j=0;j<4;j++) bfr[j] = *(const bf16x8*)&Bs[((wc + (j<<4) + ln)<<5) + (q<<3)];
    #pragma unroll
    for (int i=0;i<4;i++)
      #pragma unroll
      for (int j=0;j<4;j++)
        acc[i][j] = __builtin_amdgcn_mfma_f32_16x16x32_bf16(af[i], bfr[j], acc[i][j], 0, 0, 0);
    __syncthreads();
  }

  #pragma unroll
  for (int i=0;i<4;i++){
    const int mmb = m0 + wr + (i<<4) + (q<<2);         // global row (4096 range)
    const int bsel = mmb >> 11;                        // batch (uniform per block)
    const int sb   = mmb & 2047;                       // s within batch
    #pragma unroll
    for (int j=0;j<4;j++){
      const int n = n0 + wc + (j<<4) + ln;
      const int h = n / 192;
      const int rr = n - h*192;
      const int bh = (bsel<<4) + h;
      const float bv = bias[n];
      if (rr < 64){                                    // Q, scaled by 1/8
        u16* dst = Qb + (size_t)bh*SS*DEPTH + rr;
        #pragma unroll
        for (int r=0;r<4;r++) dst[(size_t)(sb+r)*DEPTH] = f2bf((acc[i][j][r] + bv)*0.125f);
      } else if (rr < 128){                            // K
        u16* dst = Kb + (size_t)bh*SS*DEPTH + (rr-64);
        #pragma unroll
        for (int r=0;r<4;r++) dst[(size_t)(sb+r)*DEPTH] = f2bf(acc[i][j][r] + bv);
      } else {                                         // V transposed: Vt[bh][d][s]
        ushort4 pv = { f2bf(acc[i][j][0] + bv), f2bf(acc[i][j][1] + bv),
                       f2bf(acc[i][j][2] + bv), f2bf(acc[i][j][3] + bv) };
        *(ushort4*)(Vt + ((size_t)bh*DEPTH + (rr-128))*SS + sb) = pv;
      }
    }
  }
}

// ---------------- MFMA flash attention, T14 async-stage + 2 barriers ----------------
// LDS-staged K/V (round-0 proven stride-72 layout).  Changes vs round 0:
//  (1) tile t+1 is prefetched into REGISTERS while tile t computes -> global
//      latency leaves the per-tile serial chain (T14 async-STAGE split);
//  (2) no barrier between softmax and PV: ps[w] is strictly per-wave, the
//      compiler orders the LDS RAW via lgkmcnt.  2 barriers/tile instead of 3.
__global__ __launch_bounds__(256,4) void attn_k(
    u16* __restrict__ Qb, const u16* __restrict__ Kb, const u16* __restrict__ Vt)
{
  __shared__ __align__(16) u16 Ks[64*72];      // K tile [j][d], stride 72
  __shared__ __align__(16) u16 VsT[64*72];     // V^T tile [d][j], stride 72
  __shared__ __align__(16) u16 ps[4][16*72];   // per-wave P [m][j], stride 72

  const int tid = threadIdx.x, w = tid>>6, lane = tid&63, q = lane>>4, ln = lane&15;
  const int bh = blockIdx.x;                   // b*16 + h  (XCD = bh%8)
  const int y  = blockIdx.y, sgrp = y>>3, rr_ = y&7;
  const int qt = (sgrp==0) ? 31-rr_ : (sgrp==1) ? 16+rr_ : (sgrp==2) ? 15-rr_ : rr_;
  const int r0 = qt<<6;
  const size_t kbase = (size_t)bh*SS*DEPTH;    // Kb/Qb per-(b,h) base
  const size_t vbase = (size_t)bh*DEPTH*SS;    // Vt per-(b,h) base
  const u16* __restrict__ Kp = Kb + kbase;
  const u16* __restrict__ Vp = Vt + vbase;

  // staging geometry: chunk c = p*256+tid covers (j = c>>3, d = (c&7)*8), 512 chunks
  const int j0 = tid>>3,      d0 = (tid&7)<<3;   // p=0
  const int j1 = j0 + 32,     d1 = d0;           // p=1

  bf16x8 qf[2];
  #pragma unroll
  for (int ks=0;ks<2;ks++)
    qf[ks] = *(const bf16x8*)(Qb + kbase + (size_t)(r0 + (w<<4) + ln)*DEPTH + (ks<<5) + (q<<3));

  f32x4 o[4];
  #pragma unroll
  for (int nt=0;nt<4;nt++) o[nt] = (f32x4){0.f,0.f,0.f,0.f};
  float m_r[4], l_r[4];
  #pragma unroll
  for (int r=0;r<4;r++){ m_r[r] = NEG_BIG; l_r[r] = 0.f; }

  uint4 kr0, kr1, vr0, vr1;
  #define LOADT(t) do { \
    kr0 = *(const uint4*)(Kp + (size_t)(((t)<<6)+j0)*DEPTH + d0); \
    kr1 = *(const uint4*)(Kp + (size_t)(((t)<<6)+j1)*DEPTH + d1); \
    vr0 = *(const uint4*)(Vp + (size_t)j0*SS + ((t)<<6) + d0); \
    vr1 = *(const uint4*)(Vp + (size_t)j1*SS + ((t)<<6) + d1); } while(0)

  const int T = qt + 1;
  LOADT(0);                                    // prefetch tile 0
  for (int t=0;t<T;t++){
    if (t) __syncthreads();                    // all waves done reading tile t-1
    *(uint4*)&Ks [j0*72 + d0] = kr0;           // write tile t (regs already resident)
    *(uint4*)&Ks [j1*72 + d1] = kr1;
    *(uint4*)&VsT[j0*72 + d0] = vr0;
    *(uint4*)&VsT[j1*72 + d1] = vr1;
    if (t+1 < T) LOADT(t+1);                   // issue next tile's loads; land under compute
    __syncthreads();                           // tile t visible

    // QK^T
    f32x4 sc[4];
    #pragma unroll
    for (int jt=0;jt<4;jt++) sc[jt] = (f32x4){0.f,0.f,0.f,0.f};
    #pragma unroll
    for (int ks=0;ks<2;ks++){
      #pragma unroll
      for (int jt=0;jt<4;jt++){
        bf16x8 kf = *(const bf16x8*)&Ks[((jt<<4)+ln)*72 + (ks<<5) + (q<<3)];
        sc[jt] = __builtin_amdgcn_mfma_f32_16x16x32_bf16(qf[ks], kf, sc[jt], 0, 0, 0);
      }
    }

    // causal mask on diagonal tile
    if (t == T-1){
      const int rowb = r0 + (w<<4) + (q<<2);
      #pragma unroll
      for (int jt=0;jt<4;jt++){
        const int col = (t<<6) + (jt<<4) + ln;
        #pragma unroll
        for (int r=0;r<4;r++)
          if (col > rowb + r) sc[jt][r] = NEG_BIG;
      }
    }

    // online softmax per row (row lives on 16 lanes sharing quad q)
    float alpha_r[4];
    #pragma unroll
    for (int r=0;r<4;r++){
      float mt = fmaxf(fmaxf(sc[0][r], sc[1][r]), fmaxf(sc[2][r], sc[3][r]));
      #pragma unroll
      for (int off=1; off<16; off<<=1) mt = fmaxf(mt, __shfl_xor(mt, off));
      const float mnew = fmaxf(m_r[r], mt);
      alpha_r[r] = __expf(m_r[r] - mnew);
      float p0 = __expf(sc[0][r]-mnew), p1 = __expf(sc[1][r]-mnew);
      float p2 = __expf(sc[2][r]-mnew), p3 = __expf(sc[3][r]-mnew);
      const int mrow = (q<<2) + r;
      ps[w][mrow*72 +      ln] = f2bf(p0);
      ps[w][mrow*72 + 16 + ln] = f2bf(p1);
      ps[w][mrow*72 + 32 + ln] = f2bf(p2);
      ps[w][mrow*72 + 48 + ln] = f2bf(p3);
      float psum = (p0+p1)+(p2+p3);
      #pragma unroll
      for (int off=1; off<16; off<<=1) psum += __shfl_xor(psum, off);
      l_r[r] = l_r[r]*alpha_r[r] + psum;
      m_r[r] = mnew;
    }
    #pragma unroll
    for (int nt=0;nt<4;nt++)
      #pragma unroll
      for (int r=0;r<4;r++) o[nt][r] *= alpha_r[r];

    // PV (ps is per-wave: no barrier needed, lgkmcnt orders the RAW)
    #pragma unroll
    for (int ks=0;ks<2;ks++){
      bf16x8 pa = *(const bf16x8*)&ps[w][ln*72 + (ks<<5) + (q<<3)];
      #pragma unroll
      for (int nt=0;nt<4;nt++){
        bf16x8 vf = *(const bf16x8*)&VsT[((nt<<4)+ln)*72 + (ks<<5) + (q<<3)];
        o[nt] = __builtin_amdgcn_mfma_f32_16x16x32_bf16(pa, vf, o[nt], 0, 0, 0);
      }
    }
  }
  #undef LOADT

  // epilogue: o/l -> bf16, overwrite this block's own Qb rows
  #pragma unroll
  for (int r=0;r<4;r++){
    const float rl = 1.f / fmaxf(l_r[r], 1e-30f);
    const int s = r0 + (w<<4) + (q<<2) + r;
    #pragma unroll
    for (int nt=0;nt<4;nt++)
      Qb[kbase + (size_t)s*DEPTH + (nt<<4) + ln] = f2bf(o[nt][r] * rl);
  }
}

// ---------------- out projection (m97-style staging), both batches, f32 out ----------------
// A(m,k) = Qb[(m>>11)*16 + k/64][m&2047][k%64]
__global__ __launch_bounds__(256,2) void gemm_out_k(
    const u16* __restrict__ Aq, const u16* __restrict__ Bt,
    const float* __restrict__ bias, float* __restrict__ out)
{
  const int K = DDIM;
  __shared__ __align__(16) u16 As[128*32];
  __shared__ __align__(16) u16 Bs[128*32];
  const int tid = threadIdx.x;
  const int m0 = blockIdx.x<<7, n0 = blockIdx.y<<7;
  const int bsel = m0>>11, ms = m0&2047;       // batch select (uniform per block)
  const int w = tid>>6, lane = tid&63, q = lane>>4, ln = lane&15;
  const int wr = (w>>1)<<6, wc = (w&1)<<6;

  f32x4 acc[4][4];
  #pragma unroll
  for (int i=0;i<4;i++)
    #pragma unroll
    for (int j=0;j<4;j++) acc[i][j] = (f32x4){0.f,0.f,0.f,0.f};

  const int row0 = tid>>2,       off0 = (tid&3)<<3;
  const int row1 = (tid+256)>>2, off1 = (tid&3)<<3;

  for (int k0=0;k0<K;k0+=32){
    const size_t abase = (size_t)((bsel<<4) + (k0>>6))*SS*DEPTH + (k0&63);
    GL2LDS(&Aq[abase + (size_t)(ms+row0)*DEPTH + off0], &As[(row0<<5)+off0]);
    GL2LDS(&Bt[(size_t)(n0+row0)*K + k0 + off0],        &Bs[(row0<<5)+off0]);
    GL2LDS(&Aq[abase + (size_t)(ms+row1)*DEPTH + off1], &As[(row1<<5)+off1]);
    GL2LDS(&Bt[(size_t)(n0+row1)*K + k0 + off1],        &Bs[(row1<<5)+off1]);
    __syncthreads();
    bf16x8 af[4], bfr[4];
    #pragma unroll
    for (int i=0;i<4;i++) af[i]  = *(const bf16x8*)&As[((wr + (i<<4) + ln)<<5) + (q<<3)];
    #pragma unroll
    for (int j=0;j<4;j++) bfr[j] = *(const bf16x8*)&Bs[((wc + (j<<4) + ln)<<5) + (q<<3)];
    #pragma unroll
    for (int i=0;i<4;i++)
      #pragma unroll
      for (int j=0;j<4;j++)
        acc[i][j] = __builtin_amdgcn_mfma_f32_16x16x32_bf16(af[i], bfr[j], acc[i][j], 0, 0, 0);
    __syncthreads();
  }

  #pragma unroll
  for (int i=0;i<4;i++){
    #pragma unroll
    for (int j=0;j<4;j++){
      const int n = n0 + wc + (j<<4) + ln;
      const float bv = bias[n];
      #pragma unroll
      for (int r=0;r<4;r++){
        const int mm = m0 + wr + (i<<4) + (q<<2) + r;
        out[(size_t)mm*DDIM + n] = acc[i][j][r] + bv;
      }
    }
  }
}

extern "C" void kernel_launch(void* const* d_in, const int* in_sizes, int n_in,
                              void* d_out, int out_size, void* d_ws, size_t ws_size,
                              hipStream_t stream)
{
  int ix = 0, iw = 2, ibq = 3, iwo = 4, ibo = 5;
  if (n_in == 5){ iw = 1; ibq = 2; iwo = 3; ibo = 4; }
  const float* x  = (const float*)d_in[ix];
  const float* Wq = (const float*)d_in[iw];
  const float* bq = (const float*)d_in[ibq];
  const float* Wo = (const float*)d_in[iwo];
  const float* bo = (const float*)d_in[ibo];
  float* out = (float*)d_out;

  // workspace (u16 units), total 41,943,040 B — round-1-proven footprint
  u16* ws  = (u16*)d_ws;
  u16* Wqt = ws;                                   // [3072,1024] bf16
  u16* Wot = Wqt + (size_t)QKVN*DDIM;              // [1024,1024] bf16 (bt form)
  u16* Qb  = Wot + (size_t)DDIM*DDIM;              // [B*H][S][64]; attn out aliases here
  u16* Kb  = Qb  + (size_t)BB*HH*SS*DEPTH;         // [B*H][S][64]
  u16* Vt  = Kb  + (size_t)BB*HH*SS*DEPTH;         // [B*H][64][S] (V transposed)
  u16* xb  = Vt  + (size_t)BB*HH*SS*DEPTH;         // [2,2048,1024] bf16

  convT_k<<<dim3(QKVN/32, DDIM/32), dim3(32,8), 0, stream>>>(Wq, Wqt, DDIM, QKVN);
  convT_k<<<dim3(DDIM/32, DDIM/32), dim3(32,8), 0, stream>>>(Wo, Wot, DDIM, DDIM);
  convX_k<<<dim3(BB*SS*DDIM/2048), 256, 0, stream>>>(x, xb);

  gemm_qkv_k<<<dim3(BB*SS/128, QKVN/128), 256, 0, stream>>>(xb, Wqt, bq, Qb, Kb, Vt);
  attn_k    <<<dim3(BB*HH, 32),           256, 0, stream>>>(Qb, Kb, Vt);
  gemm_out_k<<<dim3(BB*SS/128, DDIM/128), 256, 0, stream>>>(Qb, Wot, bo, out);
}

// Round 7
// 202.695 us; speedup vs baseline: 1.3581x; 1.0509x over previous
//
#include <hip/hip_runtime.h>

#define BB 2
#define SS 2048
#define DDIM 1024
#define HH 16
#define DEPTH 64
#define QKVN (3*DDIM)

typedef unsigned short u16;
typedef unsigned int u32;
typedef __attribute__((ext_vector_type(8))) short bf16x8;
typedef __attribute__((ext_vector_type(4))) float f32x4;

__device__ __forceinline__ u16 f2bf(float f){
  union{float f; u32 u;} z; z.f=f;
  u32 r = z.u + 0x7fffu + ((z.u>>16)&1u);
  return (u16)(r>>16);
}
#define NEG_BIG (-1e30f)

// async global->LDS, 16B per lane (guide m97); LDS dest must be wave-linear (ours is tid*16B)
#define GL2LDS(gp, lp) __builtin_amdgcn_global_load_lds( \
    (const __attribute__((address_space(1))) void*)(gp), \
    (__attribute__((address_space(3))) void*)(lp), 16, 0, 0)

// ---------------- transpose+convert f32 [R,C] -> bf16 [C,R] ----------------
__global__ void convT_k(const float* __restrict__ in, u16* __restrict__ out, int R, int C){
  __shared__ float tile[32][33];
  int c0 = blockIdx.x<<5, r0 = blockIdx.y<<5;
  int tx = threadIdx.x, ty = threadIdx.y;
  for (int i=ty;i<32;i+=8) tile[i][tx] = in[(size_t)(r0+i)*C + c0+tx];
  __syncthreads();
  for (int i=ty;i<32;i+=8) out[(size_t)(c0+i)*R + r0+tx] = f2bf(tile[tx][i]);
}

// ---------------- convert f32 -> bf16 flat (both batches) ----------------
__global__ void convX_k(const float* __restrict__ in, u16* __restrict__ out){
  size_t i = ((size_t)blockIdx.x*256 + threadIdx.x) * 8;
  float4 a = *(const float4*)(in + i);
  float4 b = *(const float4*)(in + i + 4);
  ushort4 lo = { f2bf(a.x), f2bf(a.y), f2bf(a.z), f2bf(a.w) };
  ushort4 hi = { f2bf(b.x), f2bf(b.y), f2bf(b.z), f2bf(b.w) };
  *(ushort4*)(out + i)     = lo;
  *(ushort4*)(out + i + 4) = hi;
}

// ---------------- QKV GEMM (m97-style: global_load_lds staging) ----------------
// [4096,1024]@[1024,3072]^T. Epilogue splits into Qb (x0.125), Kb, Vt (V transposed).
__global__ __launch_bounds__(256,2) void gemm_qkv_k(
    const u16* __restrict__ A, const u16* __restrict__ Bt,
    const float* __restrict__ bias,
    u16* __restrict__ Qb, u16* __restrict__ Kb, u16* __restrict__ Vt)
{
  const int K = DDIM;
  __shared__ __align__(16) u16 As[128*32];
  __shared__ __align__(16) u16 Bs[128*32];
  const int tid = threadIdx.x;
  const int m0 = blockIdx.x<<7, n0 = blockIdx.y<<7;
  const int w = tid>>6, lane = tid&63, q = lane>>4, ln = lane&15;
  const int wr = (w>>1)<<6, wc = (w&1)<<6;

  f32x4 acc[4][4];
  #pragma unroll
  for (int i=0;i<4;i++)
    #pragma unroll
    for (int j=0;j<4;j++) acc[i][j] = (f32x4){0.f,0.f,0.f,0.f};

  const int row0 = tid>>2,         off0 = (tid&3)<<3;
  const int row1 = (tid+256)>>2,   off1 = (tid&3)<<3;   // (tid+256)&3 == tid&3

  for (int k0=0;k0<K;k0+=32){
    GL2LDS(&A [(size_t)(m0+row0)*K + k0 + off0], &As[(row0<<5)+off0]);
    GL2LDS(&Bt[(size_t)(n0+row0)*K + k0 + off0], &Bs[(row0<<5)+off0]);
    GL2LDS(&A [(size_t)(m0+row1)*K + k0 + off1], &As[(row1<<5)+off1]);
    GL2LDS(&Bt[(size_t)(n0+row1)*K + k0 + off1], &Bs[(row1<<5)+off1]);
    __syncthreads();
    bf16x8 af[4], bfr[4];
    #pragma unroll
    for (int i=0;i<4;i++) af[i]  = *(const bf16x8*)&As[((wr + (i<<4) + ln)<<5) + (q<<3)];
    #pragma unroll
    for (int j=0;j<4;j++) bfr[j] = *(const bf16x8*)&Bs[((wc + (j<<4) + ln)<<5) + (q<<3)];
    #pragma unroll
    for (int i=0;i<4;i++)
      #pragma unroll
      for (int j=0;j<4;j++)
        acc[i][j] = __builtin_amdgcn_mfma_f32_16x16x32_bf16(af[i], bfr[j], acc[i][j], 0, 0, 0);
    __syncthreads();
  }

  #pragma unroll
  for (int i=0;i<4;i++){
    const int mmb = m0 + wr + (i<<4) + (q<<2);         // global row (4096 range)
    const int bsel = mmb >> 11;                        // batch (uniform per block)
    const int sb   = mmb & 2047;                       // s within batch
    #pragma unroll
    for (int j=0;j<4;j++){
      const int n = n0 + wc + (j<<4) + ln;
      const int h = n / 192;
      const int rr = n - h*192;
      const int bh = (bsel<<4) + h;
      const float bv = bias[n];
      if (rr < 64){                                    // Q, scaled by 1/8
        u16* dst = Qb + (size_t)bh*SS*DEPTH + rr;
        #pragma unroll
        for (int r=0;r<4;r++) dst[(size_t)(sb+r)*DEPTH] = f2bf((acc[i][j][r] + bv)*0.125f);
      } else if (rr < 128){                            // K
        u16* dst = Kb + (size_t)bh*SS*DEPTH + (rr-64);
        #pragma unroll
        for (int r=0;r<4;r++) dst[(size_t)(sb+r)*DEPTH] = f2bf(acc[i][j][r] + bv);
      } else {                                         // V transposed: Vt[bh][d][s]
        ushort4 pv = { f2bf(acc[i][j][0] + bv), f2bf(acc[i][j][1] + bv),
                       f2bf(acc[i][j][2] + bv), f2bf(acc[i][j][3] + bv) };
        *(ushort4*)(Vt + ((size_t)bh*DEPTH + (rr-128))*SS + sb) = pv;
      }
    }
  }
}

// ---------------- MFMA flash attention: T14 async-stage + MFMA row-sum ----------------
// vs round 5: the softmax SUM butterfly (4 shfl_xor x 4 rows/tile) is replaced by a
// ones-column MFMA: lacc = mfma(pa, ones, lacc) gives D[m][n] = sum_j P[m][j] with the
// same reg r <-> row (q*4+r) mapping as m_r/alpha_r.  lacc rescales by alpha like o.
// Deletes 16 cross-lane ops + 12 adds per tile-iter from the serial chain; adds 2 MFMA
// on a pipe running at 10%.
__global__ __launch_bounds__(256,4) void attn_k(
    u16* __restrict__ Qb, const u16* __restrict__ Kb, const u16* __restrict__ Vt)
{
  __shared__ __align__(16) u16 Ks[64*72];      // K tile [j][d], stride 72
  __shared__ __align__(16) u16 VsT[64*72];     // V^T tile [d][j], stride 72
  __shared__ __align__(16) u16 ps[4][16*72];   // per-wave P [m][j], stride 72

  const int tid = threadIdx.x, w = tid>>6, lane = tid&63, q = lane>>4, ln = lane&15;
  const int bh = blockIdx.x;                   // b*16 + h  (XCD = bh%8)
  const int y  = blockIdx.y, sgrp = y>>3, rr_ = y&7;
  const int qt = (sgrp==0) ? 31-rr_ : (sgrp==1) ? 16+rr_ : (sgrp==2) ? 15-rr_ : rr_;
  const int r0 = qt<<6;
  const size_t kbase = (size_t)bh*SS*DEPTH;    // Kb/Qb per-(b,h) base
  const size_t vbase = (size_t)bh*DEPTH*SS;    // Vt per-(b,h) base
  const u16* __restrict__ Kp = Kb + kbase;
  const u16* __restrict__ Vp = Vt + vbase;

  // staging geometry: chunk c = p*256+tid covers (j = c>>3, d = (c&7)*8), 512 chunks
  const int j0 = tid>>3,      d0 = (tid&7)<<3;   // p=0
  const int j1 = j0 + 32,     d1 = d0;           // p=1

  bf16x8 qf[2];
  #pragma unroll
  for (int ks=0;ks<2;ks++)
    qf[ks] = *(const bf16x8*)(Qb + kbase + (size_t)(r0 + (w<<4) + ln)*DEPTH + (ks<<5) + (q<<3));

  const bf16x8 vone = { (short)0x3F80, (short)0x3F80, (short)0x3F80, (short)0x3F80,
                        (short)0x3F80, (short)0x3F80, (short)0x3F80, (short)0x3F80 };

  f32x4 o[4];
  #pragma unroll
  for (int nt=0;nt<4;nt++) o[nt] = (f32x4){0.f,0.f,0.f,0.f};
  f32x4 lacc = (f32x4){0.f,0.f,0.f,0.f};
  float m_r[4];
  #pragma unroll
  for (int r=0;r<4;r++) m_r[r] = NEG_BIG;

  uint4 kr0, kr1, vr0, vr1;
  #define LOADT(t) do { \
    kr0 = *(const uint4*)(Kp + (size_t)(((t)<<6)+j0)*DEPTH + d0); \
    kr1 = *(const uint4*)(Kp + (size_t)(((t)<<6)+j1)*DEPTH + d1); \
    vr0 = *(const uint4*)(Vp + (size_t)j0*SS + ((t)<<6) + d0); \
    vr1 = *(const uint4*)(Vp + (size_t)j1*SS + ((t)<<6) + d1); } while(0)

  const int T = qt + 1;
  LOADT(0);                                    // prefetch tile 0
  for (int t=0;t<T;t++){
    if (t) __syncthreads();                    // all waves done reading tile t-1
    *(uint4*)&Ks [j0*72 + d0] = kr0;           // write tile t (regs already resident)
    *(uint4*)&Ks [j1*72 + d1] = kr1;
    *(uint4*)&VsT[j0*72 + d0] = vr0;
    *(uint4*)&VsT[j1*72 + d1] = vr1;
    if (t+1 < T) LOADT(t+1);                   // issue next tile's loads; land under compute
    __syncthreads();                           // tile t visible

    // QK^T
    f32x4 sc[4];
    #pragma unroll
    for (int jt=0;jt<4;jt++) sc[jt] = (f32x4){0.f,0.f,0.f,0.f};
    #pragma unroll
    for (int ks=0;ks<2;ks++){
      #pragma unroll
      for (int jt=0;jt<4;jt++){
        bf16x8 kf = *(const bf16x8*)&Ks[((jt<<4)+ln)*72 + (ks<<5) + (q<<3)];
        sc[jt] = __builtin_amdgcn_mfma_f32_16x16x32_bf16(qf[ks], kf, sc[jt], 0, 0, 0);
      }
    }

    // causal mask on diagonal tile
    if (t == T-1){
      const int rowb = r0 + (w<<4) + (q<<2);
      #pragma unroll
      for (int jt=0;jt<4;jt++){
        const int col = (t<<6) + (jt<<4) + ln;
        #pragma unroll
        for (int r=0;r<4;r++)
          if (col > rowb + r) sc[jt][r] = NEG_BIG;
      }
    }

    // online softmax per row: MAX butterfly only (sum comes from the ones-column MFMA)
    float alpha_r[4];
    #pragma unroll
    for (int r=0;r<4;r++){
      float mt = fmaxf(fmaxf(sc[0][r], sc[1][r]), fmaxf(sc[2][r], sc[3][r]));
      #pragma unroll
      for (int off=1; off<16; off<<=1) mt = fmaxf(mt, __shfl_xor(mt, off));
      const float mnew = fmaxf(m_r[r], mt);
      alpha_r[r] = __expf(m_r[r] - mnew);
      float p0 = __expf(sc[0][r]-mnew), p1 = __expf(sc[1][r]-mnew);
      float p2 = __expf(sc[2][r]-mnew), p3 = __expf(sc[3][r]-mnew);
      const int mrow = (q<<2) + r;
      ps[w][mrow*72 +      ln] = f2bf(p0);
      ps[w][mrow*72 + 16 + ln] = f2bf(p1);
      ps[w][mrow*72 + 32 + ln] = f2bf(p2);
      ps[w][mrow*72 + 48 + ln] = f2bf(p3);
      m_r[r] = mnew;
    }
    #pragma unroll
    for (int r=0;r<4;r++){
      lacc[r] *= alpha_r[r];
      #pragma unroll
      for (int nt=0;nt<4;nt++) o[nt][r] *= alpha_r[r];
    }

    // PV + row-sum (ps is per-wave: no barrier needed, lgkmcnt orders the RAW)
    #pragma unroll
    for (int ks=0;ks<2;ks++){
      bf16x8 pa = *(const bf16x8*)&ps[w][ln*72 + (ks<<5) + (q<<3)];
      lacc = __builtin_amdgcn_mfma_f32_16x16x32_bf16(pa, vone, lacc, 0, 0, 0);
      #pragma unroll
      for (int nt=0;nt<4;nt++){
        bf16x8 vf = *(const bf16x8*)&VsT[((nt<<4)+ln)*72 + (ks<<5) + (q<<3)];
        o[nt] = __builtin_amdgcn_mfma_f32_16x16x32_bf16(pa, vf, o[nt], 0, 0, 0);
      }
    }
  }
  #undef LOADT

  // epilogue: o/l -> bf16, overwrite this block's own Qb rows
  #pragma unroll
  for (int r=0;r<4;r++){
    const float rl = 1.f / fmaxf(lacc[r], 1e-30f);
    const int s = r0 + (w<<4) + (q<<2) + r;
    #pragma unroll
    for (int nt=0;nt<4;nt++)
      Qb[kbase + (size_t)s*DEPTH + (nt<<4) + ln] = f2bf(o[nt][r] * rl);
  }
}

// ---------------- out projection: 64x128 tile, 512 blocks = 2/CU ----------------
// (was 128x128 / 256 blocks = 1 block/CU -> 4 waves/CU, fully exposed barriers)
// A(m,k) = Qb[(m>>11)*16 + k/64][m&2047][k%64]
__global__ __launch_bounds__(256,2) void gemm_out_k(
    const u16* __restrict__ Aq, const u16* __restrict__ Bt,
    const float* __restrict__ bias, float* __restrict__ out)
{
  const int K = DDIM;
  __shared__ __align__(16) u16 As[64*32];
  __shared__ __align__(16) u16 Bs[128*32];
  const int tid = threadIdx.x;
  const int m0 = blockIdx.x<<6, n0 = blockIdx.y<<7;
  const int bsel = m0>>11, ms = m0&2047;       // batch select (uniform per block)
  const int w = tid>>6, lane = tid&63, q = lane>>4, ln = lane&15;
  const int wr = (w>>1)<<5, wc = (w&1)<<6;     // wave: 32 rows x 64 cols

  f32x4 acc[2][4];
  #pragma unroll
  for (int i=0;i<2;i++)
    #pragma unroll
    for (int j=0;j<4;j++) acc[i][j] = (f32x4){0.f,0.f,0.f,0.f};

  const int rowA  = tid>>2,       offA = (tid&3)<<3;   // 64 rows x 4 chunks = 256
  const int rowB0 = tid>>2,       offB = (tid&3)<<3;   // 128 rows x 4 chunks = 512
  const int rowB1 = (tid+256)>>2;

  for (int k0=0;k0<K;k0+=32){
    const size_t abase = (size_t)((bsel<<4) + (k0>>6))*SS*DEPTH + (k0&63);
    GL2LDS(&Aq[abase + (size_t)(ms+rowA)*DEPTH + offA], &As[(rowA<<5)+offA]);
    GL2LDS(&Bt[(size_t)(n0+rowB0)*K + k0 + offB],       &Bs[(rowB0<<5)+offB]);
    GL2LDS(&Bt[(size_t)(n0+rowB1)*K + k0 + offB],       &Bs[(rowB1<<5)+offB]);
    __syncthreads();
    bf16x8 af[2], bfr[4];
    #pragma unroll
    for (int i=0;i<2;i++) af[i]  = *(const bf16x8*)&As[((wr + (i<<4) + ln)<<5) + (q<<3)];
    #pragma unroll
    for (int j=0;j<4;j++) bfr[j] = *(const bf16x8*)&Bs[((wc + (j<<4) + ln)<<5) + (q<<3)];
    #pragma unroll
    for (int i=0;i<2;i++)
      #pragma unroll
      for (int j=0;j<4;j++)
        acc[i][j] = __builtin_amdgcn_mfma_f32_16x16x32_bf16(af[i], bfr[j], acc[i][j], 0, 0, 0);
    __syncthreads();
  }

  #pragma unroll
  for (int i=0;i<2;i++){
    #pragma unroll
    for (int j=0;j<4;j++){
      const int n = n0 + wc + (j<<4) + ln;
      const float bv = bias[n];
      #pragma unroll
      for (int r=0;r<4;r++){
        const int mm = m0 + wr + (i<<4) + (q<<2) + r;
        out[(size_t)mm*DDIM + n] = acc[i][j][r] + bv;
      }
    }
  }
}

extern "C" void kernel_launch(void* const* d_in, const int* in_sizes, int n_in,
                              void* d_out, int out_size, void* d_ws, size_t ws_size,
                              hipStream_t stream)
{
  int ix = 0, iw = 2, ibq = 3, iwo = 4, ibo = 5;
  if (n_in == 5){ iw = 1; ibq = 2; iwo = 3; ibo = 4; }
  const float* x  = (const float*)d_in[ix];
  const float* Wq = (const float*)d_in[iw];
  const float* bq = (const float*)d_in[ibq];
  const float* Wo = (const float*)d_in[iwo];
  const float* bo = (const float*)d_in[ibo];
  float* out = (float*)d_out;

  // workspace (u16 units), total 41,943,040 B — round-1-proven footprint
  u16* ws  = (u16*)d_ws;
  u16* Wqt = ws;                                   // [3072,1024] bf16
  u16* Wot = Wqt + (size_t)QKVN*DDIM;              // [1024,1024] bf16 (bt form)
  u16* Qb  = Wot + (size_t)DDIM*DDIM;              // [B*H][S][64]; attn out aliases here
  u16* Kb  = Qb  + (size_t)BB*HH*SS*DEPTH;         // [B*H][S][64]
  u16* Vt  = Kb  + (size_t)BB*HH*SS*DEPTH;         // [B*H][64][S] (V transposed)
  u16* xb  = Vt  + (size_t)BB*HH*SS*DEPTH;         // [2,2048,1024] bf16

  convT_k<<<dim3(QKVN/32, DDIM/32), dim3(32,8), 0, stream>>>(Wq, Wqt, DDIM, QKVN);
  convT_k<<<dim3(DDIM/32, DDIM/32), dim3(32,8), 0, stream>>>(Wo, Wot, DDIM, DDIM);
  convX_k<<<dim3(BB*SS*DDIM/2048), 256, 0, stream>>>(x, xb);

  gemm_qkv_k<<<dim3(BB*SS/128, QKVN/128), 256, 0, stream>>>(xb, Wqt, bq, Qb, Kb, Vt);
  attn_k    <<<dim3(BB*HH, 32),           256, 0, stream>>>(Qb, Kb, Vt);
  gemm_out_k<<<dim3(BB*SS/64,  DDIM/128), 256, 0, stream>>>(Qb, Wot, bo, out);
}